// Round 1
// baseline (240.457 us; speedup 1.0000x reference)
//
#include <hip/hip_runtime.h>
#include <stdint.h>

#define NQ 8192
#define BSZ 8
#define NH 8
#define NP 4
#define HD 32
#define EMBED 256
#define IMG 128          // H == W == 128
#define NPIX (IMG*IMG)

typedef __attribute__((ext_vector_type(8))) short short8v;   // 8 bf16 (4 VGPR)
typedef __attribute__((ext_vector_type(4))) float f32x4;

static __device__ __forceinline__ float bf2f(uint32_t u) {
    union { uint32_t i; float f; } x; x.i = u << 16; return x.f;
}
static __device__ __forceinline__ uint16_t f2bf(float f) {
    union { float f; uint32_t i; } x; x.f = f;
    uint32_t r = x.i + 0x7fffu + ((x.i >> 16) & 1u);   // RNE
    return (uint16_t)(r >> 16);
}
static __device__ __forceinline__ void gload_lds16(const void* g, void* l) {
    __builtin_amdgcn_global_load_lds(
        (const __attribute__((address_space(1))) unsigned int*)g,
        (__attribute__((address_space(3))) unsigned int*)l, 16, 0, 0);
}

// ---------------------------------------------------------------------------
// pack: build transposed bf16 weights.  wT[n][k] = w[k][n]
//   wTval, wTout: [256][256]; wTcat: [96][256] (rows 0..63 = w_off cols,
//   rows 64..95 = w_attn cols)
// ---------------------------------------------------------------------------
__global__ void pack_w(const float* __restrict__ w_val, const float* __restrict__ w_out,
                       const float* __restrict__ w_off, const float* __restrict__ w_attn,
                       uint16_t* __restrict__ wTval, uint16_t* __restrict__ wTout,
                       uint16_t* __restrict__ wTcat) {
    int k = blockIdx.x;          // 0..255
    int n = threadIdx.x;         // 0..255
    wTval[n * 256 + k] = f2bf(w_val[k * 256 + n]);
    wTout[n * 256 + k] = f2bf(w_out[k * 256 + n]);
    if (n < 64)       wTcat[n * 256 + k]        = f2bf(w_off[k * 64 + n]);
    else if (n < 96)  wTcat[n * 256 + k]        = f2bf(w_attn[k * 32 + (n - 64)]);
}

// ---------------------------------------------------------------------------
// GEMM  C[M x 256] = A[M x 256] * B[256 x 256] (+bias), K=256
//  A: f32 (inline cvt->bf16) or bf16;  B: pre-transposed bf16 BT[n][k]
//  OUT_F32: write f32 + bias; else bf16 + bias.
//  128x128 tile, BK=64, 4 waves (2x2 of 64x64), 16x16x32 MFMA,
//  XOR-swizzled LDS (byte ^= (row&7)<<4), 2-phase double buffer.
// ---------------------------------------------------------------------------
template<bool A_F32, bool OUT_F32>
__global__ __launch_bounds__(256, 2)
void gemm_k256(const void* __restrict__ Ap, const uint16_t* __restrict__ BT,
               void* __restrict__ Cp, const float* __restrict__ bias, int M) {
    __shared__ uint16_t As[2][128 * 64];   // 16KB each, [row][k] bf16, swizzled
    __shared__ uint16_t Bs[2][128 * 64];
    const int tid = threadIdx.x;
    const int w = tid >> 6, l = tid & 63;
    const int bm = blockIdx.x, bn = blockIdx.y;

    f32x4 acc[4][4] = {};

    auto stageB = [&](int buf, int kt) {
#pragma unroll
        for (int c = 0; c < 4; ++c) {
            int loff = (w * 4 + c) * 1024 + l * 16;
            int row = loff >> 7, colb = loff & 127;
            const char* src = (const char*)BT + (size_t)(bn * 128 + row) * 512
                              + kt * 128 + (colb ^ ((row & 7) << 4));
            gload_lds16(src, (char*)&Bs[buf][0] + (w * 4 + c) * 1024);
        }
    };
    auto stageA = [&](int buf, int kt) {
        if constexpr (!A_F32) {
#pragma unroll
            for (int c = 0; c < 4; ++c) {
                int loff = (w * 4 + c) * 1024 + l * 16;
                int row = loff >> 7, colb = loff & 127;
                const char* src = (const char*)Ap + (size_t)(bm * 128 + row) * 512
                                  + kt * 128 + (colb ^ ((row & 7) << 4));
                gload_lds16(src, (char*)&As[buf][0] + (w * 4 + c) * 1024);
            }
        } else {
#pragma unroll
            for (int c = 0; c < 4; ++c) {
                int loff = tid * 16 + c * 4096;
                int row = loff >> 7, colb = loff & 127;
                const float* src = (const float*)Ap + (size_t)(bm * 128 + row) * 256
                                   + kt * 64 + (colb >> 1);
                float4 f0 = *(const float4*)src;
                float4 f1 = *(const float4*)(src + 4);
                uint4 pk;
                pk.x = (uint32_t)f2bf(f0.x) | ((uint32_t)f2bf(f0.y) << 16);
                pk.y = (uint32_t)f2bf(f0.z) | ((uint32_t)f2bf(f0.w) << 16);
                pk.z = (uint32_t)f2bf(f1.x) | ((uint32_t)f2bf(f1.y) << 16);
                pk.w = (uint32_t)f2bf(f1.z) | ((uint32_t)f2bf(f1.w) << 16);
                *(uint4*)((char*)&As[buf][0] + row * 128 + (colb ^ ((row & 7) << 4))) = pk;
            }
        }
    };

    const int wr = (w >> 1) * 64, wc = (w & 1) * 64;
    int buf = 0;
    stageA(0, 0); stageB(0, 0);
    __syncthreads();
#pragma unroll
    for (int kt = 0; kt < 4; ++kt) {
        if (kt < 3) { stageA(buf ^ 1, kt + 1); stageB(buf ^ 1, kt + 1); }
#pragma unroll
        for (int ks = 0; ks < 2; ++ks) {
            short8v a[4], b[4];
            const int kb = ks * 64 + (l >> 4) * 16;
#pragma unroll
            for (int m = 0; m < 4; ++m) {
                int row = wr + m * 16 + (l & 15);
                a[m] = *(const short8v*)((const char*)&As[buf][0] + row * 128
                                         + (kb ^ ((row & 7) << 4)));
            }
#pragma unroll
            for (int n = 0; n < 4; ++n) {
                int col = wc + n * 16 + (l & 15);
                b[n] = *(const short8v*)((const char*)&Bs[buf][0] + col * 128
                                         + (kb ^ ((col & 7) << 4)));
            }
#pragma unroll
            for (int m = 0; m < 4; ++m)
#pragma unroll
                for (int n = 0; n < 4; ++n)
                    acc[m][n] = __builtin_amdgcn_mfma_f32_16x16x32_bf16(a[m], b[n], acc[m][n], 0, 0, 0);
        }
        __syncthreads();
        buf ^= 1;
    }

    const int r0 = bm * 128 + wr + ((l >> 4) * 4);
    const int c0 = bn * 128 + wc + (l & 15);
#pragma unroll
    for (int m = 0; m < 4; ++m)
#pragma unroll
        for (int n = 0; n < 4; ++n) {
            int col = c0 + n * 16;
            float bv = bias[col];
            if constexpr (OUT_F32) {
                float* C = (float*)Cp;
#pragma unroll
                for (int r = 0; r < 4; ++r)
                    C[(size_t)(r0 + m * 16 + r) * 256 + col] = acc[m][n][r] + bv;
            } else {
                uint16_t* C = (uint16_t*)Cp;
#pragma unroll
                for (int r = 0; r < 4; ++r)
                    C[(size_t)(r0 + m * 16 + r) * 256 + col] = f2bf(acc[m][n][r] + bv);
            }
        }
}

// ---------------------------------------------------------------------------
// proj: per 64 query rows, GEMM query[64x256] @ wTcat^T -> scores[64x96],
// then per (row, head): softmax over 4 attn logits, sampling locations.
//   locs[item][p][2] = (px,py) f32   with px = ref_x*128 + off_x - 0.5
//   attnw[item][p]   = softmax weight
//   item = (b*NQ + q)*NH + h
// ---------------------------------------------------------------------------
__global__ __launch_bounds__(256, 2)
void proj_kernel(const float* __restrict__ Q, const uint16_t* __restrict__ WTcat,
                 const float* __restrict__ b_off, const float* __restrict__ b_attn,
                 const float* __restrict__ refp,
                 float* __restrict__ locs, float* __restrict__ attnw) {
    __shared__ uint16_t Bs[96 * 256];   // 48KB, [col][k], swizzled
    __shared__ uint16_t As[64 * 256];   // 32KB, [row][k], swizzled; reused as scores
    const int tid = threadIdx.x, w = tid >> 6, l = tid & 63;
    const int blk = blockIdx.x;

    // stage all of wTcat (48KB = 48 x 1KB wave chunks)
#pragma unroll
    for (int c = 0; c < 12; ++c) {
        int loff = (w * 12 + c) * 1024;
        int lofl = loff + l * 16;
        int row = lofl >> 9, colb = lofl & 511;
        const char* src = (const char*)WTcat + (size_t)row * 512 + (colb ^ ((row & 7) << 4));
        gload_lds16(src, (char*)Bs + loff);
    }
    // stage 64 query rows, f32 -> bf16
#pragma unroll
    for (int c = 0; c < 8; ++c) {
        int loff = tid * 16 + c * 4096;
        int row = loff >> 9, colb = loff & 511;
        const float* src = Q + (size_t)(blk * 64 + row) * 256 + (colb >> 1);
        float4 f0 = *(const float4*)src;
        float4 f1 = *(const float4*)(src + 4);
        uint4 pk;
        pk.x = (uint32_t)f2bf(f0.x) | ((uint32_t)f2bf(f0.y) << 16);
        pk.y = (uint32_t)f2bf(f0.z) | ((uint32_t)f2bf(f0.w) << 16);
        pk.z = (uint32_t)f2bf(f1.x) | ((uint32_t)f2bf(f1.y) << 16);
        pk.w = (uint32_t)f2bf(f1.z) | ((uint32_t)f2bf(f1.w) << 16);
        *(uint4*)((char*)As + row * 512 + (colb ^ ((row & 7) << 4))) = pk;
    }
    __syncthreads();

    f32x4 acc[6] = {};
    const int arow = w * 16 + (l & 15);
#pragma unroll
    for (int ks = 0; ks < 8; ++ks) {
        const int kb = ks * 64 + (l >> 4) * 16;
        short8v a = *(const short8v*)((const char*)As + arow * 512 + (kb ^ ((arow & 7) << 4)));
#pragma unroll
        for (int n = 0; n < 6; ++n) {
            int col = n * 16 + (l & 15);
            short8v b = *(const short8v*)((const char*)Bs + col * 512 + (kb ^ ((col & 7) << 4)));
            acc[n] = __builtin_amdgcn_mfma_f32_16x16x32_bf16(a, b, acc[n], 0, 0, 0);
        }
    }
    __syncthreads();
    float* scores = (float*)As;   // [64][96]
#pragma unroll
    for (int n = 0; n < 6; ++n)
#pragma unroll
        for (int r = 0; r < 4; ++r)
            scores[(w * 16 + (l >> 4) * 4 + r) * 96 + n * 16 + (l & 15)] = acc[n][r];
    __syncthreads();

    for (int it = tid; it < 512; it += 256) {
        int row = it >> 3, h = it & 7;
        int gq = blk * 64 + row;
        size_t gitem = (size_t)gq * NH + h;
        float s0 = scores[row * 96 + 64 + h * 4 + 0] + b_attn[h * 4 + 0];
        float s1 = scores[row * 96 + 64 + h * 4 + 1] + b_attn[h * 4 + 1];
        float s2 = scores[row * 96 + 64 + h * 4 + 2] + b_attn[h * 4 + 2];
        float s3 = scores[row * 96 + 64 + h * 4 + 3] + b_attn[h * 4 + 3];
        float mx = fmaxf(fmaxf(s0, s1), fmaxf(s2, s3));
        float e0 = __expf(s0 - mx), e1 = __expf(s1 - mx);
        float e2 = __expf(s2 - mx), e3 = __expf(s3 - mx);
        float inv = 1.0f / (e0 + e1 + e2 + e3);
        float rx = refp[gq * 2 + 0] * 128.0f - 0.5f;
        float ry = refp[gq * 2 + 1] * 128.0f - 0.5f;
        float ew[4] = { e0, e1, e2, e3 };
#pragma unroll
        for (int p = 0; p < 4; ++p) {
            float ox = scores[row * 96 + h * 8 + p * 2 + 0] + b_off[h * 8 + p * 2 + 0];
            float oy = scores[row * 96 + h * 8 + p * 2 + 1] + b_off[h * 8 + p * 2 + 1];
            locs[gitem * 8 + p * 2 + 0] = rx + ox;
            locs[gitem * 8 + p * 2 + 1] = ry + oy;
            attnw[gitem * 4 + p] = ew[p] * inv;
        }
    }
}

// ---------------------------------------------------------------------------
// sample: 16 lanes per item (item = (b,q,h)), each lane owns 2 dims.
// Per point: 4 bilinear corners, zero padding out of range.
//   out_attn[b,q,h*32+d] bf16
// ---------------------------------------------------------------------------
__global__ __launch_bounds__(256)
void sample_kernel(const uint16_t* __restrict__ v, const float* __restrict__ locs,
                   const float* __restrict__ attnw, uint16_t* __restrict__ oatt) {
    int t = blockIdx.x * 256 + threadIdx.x;
    int item = t >> 4;           // (b*NQ+q)*NH + h  -- 524288 items
    int lane = t & 15;           // dim pair: d0 = lane*2
    int h = item & 7;
    int bq = item >> 3;
    int b = bq >> 13;
    const uint32_t* vp = (const uint32_t*)v + ((size_t)b * NPIX * 128) + h * 16 + lane;
    float acc0 = 0.f, acc1 = 0.f;
#pragma unroll
    for (int p = 0; p < 4; ++p) {
        float px = locs[(size_t)item * 8 + p * 2 + 0];
        float py = locs[(size_t)item * 8 + p * 2 + 1];
        float aw = attnw[(size_t)item * 4 + p];
        float fx = floorf(px), fy = floorf(py);
        float wx = px - fx, wy = py - fy;
        int x0 = (int)fx, y0 = (int)fy;
#pragma unroll
        for (int cy = 0; cy < 2; ++cy)
#pragma unroll
            for (int cx = 0; cx < 2; ++cx) {
                int xx = x0 + cx, yy = y0 + cy;
                if (xx >= 0 && xx < IMG && yy >= 0 && yy < IMG) {
                    float wgt = aw * (cx ? wx : 1.f - wx) * (cy ? wy : 1.f - wy);
                    uint32_t u = vp[(size_t)(yy * IMG + xx) * 128];
                    acc0 += wgt * bf2f(u & 0xffffu);
                    acc1 += wgt * bf2f(u >> 16);
                }
            }
    }
    uint32_t out = ((uint32_t)f2bf(acc1) << 16) | f2bf(acc0);
    ((uint32_t*)oatt)[(size_t)bq * 128 + h * 16 + lane] = out;
}

// ---------------------------------------------------------------------------
extern "C" void kernel_launch(void* const* d_in, const int* in_sizes, int n_in,
                              void* d_out, int out_size, void* d_ws, size_t ws_size,
                              hipStream_t stream) {
    const float* query  = (const float*)d_in[0];
    const float* refp   = (const float*)d_in[1];
    const float* value  = (const float*)d_in[2];
    const float* w_off  = (const float*)d_in[3];
    const float* b_off  = (const float*)d_in[4];
    const float* w_attn = (const float*)d_in[5];
    const float* b_attn = (const float*)d_in[6];
    const float* w_val  = (const float*)d_in[7];
    const float* b_val  = (const float*)d_in[8];
    const float* w_out  = (const float*)d_in[9];
    const float* b_out  = (const float*)d_in[10];

    char* ws = (char*)d_ws;
    uint16_t* v     = (uint16_t*)(ws);                    //  67108864 B
    uint16_t* oatt  = (uint16_t*)(ws + 67108864);         //  33554432 B
    float*    locs  = (float*)(ws + 100663296);           //  16777216 B
    float*    attnw = (float*)(ws + 117440512);           //   8388608 B
    uint16_t* wTval = (uint16_t*)(ws + 125829120);        //    131072 B
    uint16_t* wTout = (uint16_t*)(ws + 125960192);        //    131072 B
    uint16_t* wTcat = (uint16_t*)(ws + 126091264);        //     49152 B

    pack_w<<<256, 256, 0, stream>>>(w_val, w_out, w_off, w_attn, wTval, wTout, wTcat);
    // value projection: [131072 x 256] f32 @ wTval -> v bf16
    gemm_k256<true, false><<<dim3(1024, 2), 256, 0, stream>>>(value, wTval, v, b_val, 131072);
    // query projections + softmax + locations
    proj_kernel<<<1024, 256, 0, stream>>>(query, wTcat, b_off, b_attn, refp, locs, attnw);
    // bilinear sampling -> out_attn bf16
    sample_kernel<<<32768, 256, 0, stream>>>(v, locs, attnw, oatt);
    // output projection: [65536 x 256] bf16 @ wTout + b_out -> f32 d_out
    gemm_k256<false, true><<<dim3(512, 2), 256, 0, stream>>>(oatt, wTout, (float*)d_out, b_out, 65536);
}

// Round 2
// 184.381 us; speedup vs baseline: 1.3041x; 1.3041x over previous
//
#include <hip/hip_runtime.h>
#include <stdint.h>

#define NQ 8192
#define BSZ 8
#define NH 8
#define NP 4
#define HD 32
#define EMBED 256
#define IMG 128          // H == W == 128
#define NPIX (IMG*IMG)

typedef __attribute__((ext_vector_type(8))) short short8v;   // 8 bf16 (4 VGPR)
typedef __attribute__((ext_vector_type(4))) float f32x4;

static __device__ __forceinline__ float bf2f(uint32_t u) {
    union { uint32_t i; float f; } x; x.i = u << 16; return x.f;
}
static __device__ __forceinline__ uint16_t f2bf(float f) {
    union { float f; uint32_t i; } x; x.f = f;
    uint32_t r = x.i + 0x7fffu + ((x.i >> 16) & 1u);   // RNE
    return (uint16_t)(r >> 16);
}
static __device__ __forceinline__ void gload_lds16(const void* g, void* l) {
    __builtin_amdgcn_global_load_lds(
        (const __attribute__((address_space(1))) unsigned int*)g,
        (__attribute__((address_space(3))) unsigned int*)l, 16, 0, 0);
}

// ---------------------------------------------------------------------------
// pack: build transposed bf16 weights.  wT[n][k] = w[k][n]
// ---------------------------------------------------------------------------
__global__ void pack_w(const float* __restrict__ w_val, const float* __restrict__ w_out,
                       const float* __restrict__ w_off, const float* __restrict__ w_attn,
                       uint16_t* __restrict__ wTval, uint16_t* __restrict__ wTout,
                       uint16_t* __restrict__ wTcat) {
    int k = blockIdx.x;          // 0..255
    int n = threadIdx.x;         // 0..255
    wTval[n * 256 + k] = f2bf(w_val[k * 256 + n]);
    wTout[n * 256 + k] = f2bf(w_out[k * 256 + n]);
    if (n < 64)       wTcat[n * 256 + k]        = f2bf(w_off[k * 64 + n]);
    else if (n < 96)  wTcat[n * 256 + k]        = f2bf(w_attn[k * 32 + (n - 64)]);
}

// ---------------------------------------------------------------------------
// GEMM  C[M x 256] = A[M x 256] * B[256 x 256] (+bias), K=256
//  PLANE: C is v[b][h][pix][32] bf16 (b = row>>14, pix = row&16383,
//         h = col>>5, d = col&31); else row-major [M][256].
// ---------------------------------------------------------------------------
template<bool A_F32, bool OUT_F32, bool PLANE>
__global__ __launch_bounds__(256, 2)
void gemm_k256(const void* __restrict__ Ap, const uint16_t* __restrict__ BT,
               void* __restrict__ Cp, const float* __restrict__ bias, int M) {
    __shared__ uint16_t As[2][128 * 64];   // 16KB each, [row][k] bf16, swizzled
    __shared__ uint16_t Bs[2][128 * 64];
    const int tid = threadIdx.x;
    const int w = tid >> 6, l = tid & 63;
    const int bm = blockIdx.x, bn = blockIdx.y;

    f32x4 acc[4][4] = {};

    auto stageB = [&](int buf, int kt) {
#pragma unroll
        for (int c = 0; c < 4; ++c) {
            int loff = (w * 4 + c) * 1024 + l * 16;
            int row = loff >> 7, colb = loff & 127;
            const char* src = (const char*)BT + (size_t)(bn * 128 + row) * 512
                              + kt * 128 + (colb ^ ((row & 7) << 4));
            gload_lds16(src, (char*)&Bs[buf][0] + (w * 4 + c) * 1024);
        }
    };
    auto stageA = [&](int buf, int kt) {
        if constexpr (!A_F32) {
#pragma unroll
            for (int c = 0; c < 4; ++c) {
                int loff = (w * 4 + c) * 1024 + l * 16;
                int row = loff >> 7, colb = loff & 127;
                const char* src = (const char*)Ap + (size_t)(bm * 128 + row) * 512
                                  + kt * 128 + (colb ^ ((row & 7) << 4));
                gload_lds16(src, (char*)&As[buf][0] + (w * 4 + c) * 1024);
            }
        } else {
#pragma unroll
            for (int c = 0; c < 4; ++c) {
                int loff = tid * 16 + c * 4096;
                int row = loff >> 7, colb = loff & 127;
                const float* src = (const float*)Ap + (size_t)(bm * 128 + row) * 256
                                   + kt * 64 + (colb >> 1);
                float4 f0 = *(const float4*)src;
                float4 f1 = *(const float4*)(src + 4);
                uint4 pk;
                pk.x = (uint32_t)f2bf(f0.x) | ((uint32_t)f2bf(f0.y) << 16);
                pk.y = (uint32_t)f2bf(f0.z) | ((uint32_t)f2bf(f0.w) << 16);
                pk.z = (uint32_t)f2bf(f1.x) | ((uint32_t)f2bf(f1.y) << 16);
                pk.w = (uint32_t)f2bf(f1.z) | ((uint32_t)f2bf(f1.w) << 16);
                *(uint4*)((char*)&As[buf][0] + row * 128 + (colb ^ ((row & 7) << 4))) = pk;
            }
        }
    };

    const int wr = (w >> 1) * 64, wc = (w & 1) * 64;
    int buf = 0;
    stageA(0, 0); stageB(0, 0);
    __syncthreads();
#pragma unroll
    for (int kt = 0; kt < 4; ++kt) {
        if (kt < 3) { stageA(buf ^ 1, kt + 1); stageB(buf ^ 1, kt + 1); }
#pragma unroll
        for (int ks = 0; ks < 2; ++ks) {
            short8v a[4], b[4];
            const int kb = ks * 64 + (l >> 4) * 16;
#pragma unroll
            for (int m = 0; m < 4; ++m) {
                int row = wr + m * 16 + (l & 15);
                a[m] = *(const short8v*)((const char*)&As[buf][0] + row * 128
                                         + (kb ^ ((row & 7) << 4)));
            }
#pragma unroll
            for (int n = 0; n < 4; ++n) {
                int col = wc + n * 16 + (l & 15);
                b[n] = *(const short8v*)((const char*)&Bs[buf][0] + col * 128
                                         + (kb ^ ((col & 7) << 4)));
            }
#pragma unroll
            for (int m = 0; m < 4; ++m)
#pragma unroll
                for (int n = 0; n < 4; ++n)
                    acc[m][n] = __builtin_amdgcn_mfma_f32_16x16x32_bf16(a[m], b[n], acc[m][n], 0, 0, 0);
        }
        __syncthreads();
        buf ^= 1;
    }

    const int r0 = bm * 128 + wr + ((l >> 4) * 4);
    const int c0 = bn * 128 + wc + (l & 15);
#pragma unroll
    for (int m = 0; m < 4; ++m)
#pragma unroll
        for (int n = 0; n < 4; ++n) {
            int col = c0 + n * 16;
            float bv = bias[col];
#pragma unroll
            for (int r = 0; r < 4; ++r) {
                int row = r0 + m * 16 + r;
                float val = acc[m][n][r] + bv;
                if constexpr (OUT_F32) {
                    ((float*)Cp)[(size_t)row * 256 + col] = val;
                } else if constexpr (PLANE) {
                    int b_ = row >> 14, pix = row & 16383;
                    int h_ = col >> 5, d_ = col & 31;
                    ((uint16_t*)Cp)[((((size_t)(b_ * 8 + h_)) << 14 | pix) << 5) + d_] = f2bf(val);
                } else {
                    ((uint16_t*)Cp)[(size_t)row * 256 + col] = f2bf(val);
                }
            }
        }
}

// ---------------------------------------------------------------------------
// proj: per 64 query rows, GEMM query[64x256] @ wTcat^T -> scores[64x96],
// then per (row, head): softmax + sampling locations, written HEAD-MAJOR:
//   itemH = ((b*8+h)*8192 + q);  locs[itemH][8], attnw[itemH][4]
// ---------------------------------------------------------------------------
__global__ __launch_bounds__(256, 2)
void proj_kernel(const float* __restrict__ Q, const uint16_t* __restrict__ WTcat,
                 const float* __restrict__ b_off, const float* __restrict__ b_attn,
                 const float* __restrict__ refp,
                 float* __restrict__ locs, float* __restrict__ attnw) {
    __shared__ uint16_t Bs[96 * 256];   // 48KB, [col][k], swizzled
    __shared__ uint16_t As[64 * 256];   // 32KB, [row][k], swizzled; reused as scores
    const int tid = threadIdx.x, w = tid >> 6, l = tid & 63;
    const int blk = blockIdx.x;

#pragma unroll
    for (int c = 0; c < 12; ++c) {
        int loff = (w * 12 + c) * 1024;
        int lofl = loff + l * 16;
        int row = lofl >> 9, colb = lofl & 511;
        const char* src = (const char*)WTcat + (size_t)row * 512 + (colb ^ ((row & 7) << 4));
        gload_lds16(src, (char*)Bs + loff);
    }
#pragma unroll
    for (int c = 0; c < 8; ++c) {
        int loff = tid * 16 + c * 4096;
        int row = loff >> 9, colb = loff & 511;
        const float* src = Q + (size_t)(blk * 64 + row) * 256 + (colb >> 1);
        float4 f0 = *(const float4*)src;
        float4 f1 = *(const float4*)(src + 4);
        uint4 pk;
        pk.x = (uint32_t)f2bf(f0.x) | ((uint32_t)f2bf(f0.y) << 16);
        pk.y = (uint32_t)f2bf(f0.z) | ((uint32_t)f2bf(f0.w) << 16);
        pk.z = (uint32_t)f2bf(f1.x) | ((uint32_t)f2bf(f1.y) << 16);
        pk.w = (uint32_t)f2bf(f1.z) | ((uint32_t)f2bf(f1.w) << 16);
        *(uint4*)((char*)As + row * 512 + (colb ^ ((row & 7) << 4))) = pk;
    }
    __syncthreads();

    f32x4 acc[6] = {};
    const int arow = w * 16 + (l & 15);
#pragma unroll
    for (int ks = 0; ks < 8; ++ks) {
        const int kb = ks * 64 + (l >> 4) * 16;
        short8v a = *(const short8v*)((const char*)As + arow * 512 + (kb ^ ((arow & 7) << 4)));
#pragma unroll
        for (int n = 0; n < 6; ++n) {
            int col = n * 16 + (l & 15);
            short8v b = *(const short8v*)((const char*)Bs + col * 512 + (kb ^ ((col & 7) << 4)));
            acc[n] = __builtin_amdgcn_mfma_f32_16x16x32_bf16(a, b, acc[n], 0, 0, 0);
        }
    }
    __syncthreads();
    float* scores = (float*)As;   // [64][96]
#pragma unroll
    for (int n = 0; n < 6; ++n)
#pragma unroll
        for (int r = 0; r < 4; ++r)
            scores[(w * 16 + (l >> 4) * 4 + r) * 96 + n * 16 + (l & 15)] = acc[n][r];
    __syncthreads();

    for (int it = tid; it < 512; it += 256) {
        int row = it >> 3, h = it & 7;
        int gq = blk * 64 + row;                       // b*NQ + q
        int b = gq >> 13, q = gq & 8191;
        size_t itemH = ((size_t)(b * 8 + h) << 13) | q;
        float s0 = scores[row * 96 + 64 + h * 4 + 0] + b_attn[h * 4 + 0];
        float s1 = scores[row * 96 + 64 + h * 4 + 1] + b_attn[h * 4 + 1];
        float s2 = scores[row * 96 + 64 + h * 4 + 2] + b_attn[h * 4 + 2];
        float s3 = scores[row * 96 + 64 + h * 4 + 3] + b_attn[h * 4 + 3];
        float mx = fmaxf(fmaxf(s0, s1), fmaxf(s2, s3));
        float e0 = __expf(s0 - mx), e1 = __expf(s1 - mx);
        float e2 = __expf(s2 - mx), e3 = __expf(s3 - mx);
        float inv = 1.0f / (e0 + e1 + e2 + e3);
        float rx = refp[gq * 2 + 0] * 128.0f - 0.5f;
        float ry = refp[gq * 2 + 1] * 128.0f - 0.5f;
        float ew[4] = { e0, e1, e2, e3 };
#pragma unroll
        for (int p = 0; p < 4; ++p) {
            float ox = scores[row * 96 + h * 8 + p * 2 + 0] + b_off[h * 8 + p * 2 + 0];
            float oy = scores[row * 96 + h * 8 + p * 2 + 1] + b_off[h * 8 + p * 2 + 1];
            locs[itemH * 8 + p * 2 + 0] = rx + ox;
            locs[itemH * 8 + p * 2 + 1] = ry + oy;
            attnw[itemH * 4 + p] = ew[p] * inv;
        }
    }
}

// ---------------------------------------------------------------------------
// sample v2: plane-major v[b][h][16384][32] bf16 (1MB per (b,h) plane).
// XCD-pinned: blockIdx&7 = h -> each XCD streams one head's planes in order,
// so the active plane stays L2-resident (1-2 MB << 4 MB/XCD).
// 4 lanes per item (dg = 8 dims each), dwordx4 gathers.
// ---------------------------------------------------------------------------
__global__ __launch_bounds__(256)
void sample_kernel(const uint16_t* __restrict__ v, const float* __restrict__ locs,
                   const float* __restrict__ attnw, uint16_t* __restrict__ oatt) {
    const int bid = blockIdx.x;          // 8192 blocks
    const int h = bid & 7;
    const int rest = bid >> 3;           // 0..1023
    const int b = rest >> 7;             // 0..7
    const int chunk = rest & 127;        // 0..127
    const int qloc = threadIdx.x >> 2;   // 0..63
    const int dg = threadIdx.x & 3;      // dims dg*8..dg*8+7
    const int q = chunk * 64 + qloc;
    const size_t itemH = ((size_t)(b * 8 + h) << 13) | q;
    const char* plane = (const char*)v + ((size_t)(b * 8 + h) << 20);   // 1MB planes

    float4 l01 = ((const float4*)locs)[itemH * 2 + 0];
    float4 l23 = ((const float4*)locs)[itemH * 2 + 1];
    float4 aw4 = ((const float4*)attnw)[itemH];
    float pxs[4] = { l01.x, l01.z, l23.x, l23.z };
    float pys[4] = { l01.y, l01.w, l23.y, l23.w };
    float aws[4] = { aw4.x, aw4.y, aw4.z, aw4.w };

    float acc[8] = {};
#pragma unroll
    for (int p = 0; p < 4; ++p) {
        float px = pxs[p], py = pys[p], aw = aws[p];
        float fx = floorf(px), fy = floorf(py);
        float wx = px - fx, wy = py - fy;
        int x0 = (int)fx, y0 = (int)fy;
#pragma unroll
        for (int cy = 0; cy < 2; ++cy) {
            int yy = y0 + cy;
            float wyv = cy ? wy : 1.f - wy;
            bool yok = (unsigned)yy < (unsigned)IMG;
            int yc = min(max(yy, 0), IMG - 1);
#pragma unroll
            for (int cx = 0; cx < 2; ++cx) {
                int xx = x0 + cx;
                bool ok = yok && ((unsigned)xx < (unsigned)IMG);
                int xc = min(max(xx, 0), IMG - 1);
                float wgt = ok ? aw * (cx ? wx : 1.f - wx) * wyv : 0.f;
                const uint4 u = *(const uint4*)(plane + ((size_t)(yc * IMG + xc) << 6) + dg * 16);
                acc[0] += wgt * bf2f(u.x & 0xffffu);
                acc[1] += wgt * bf2f(u.x >> 16);
                acc[2] += wgt * bf2f(u.y & 0xffffu);
                acc[3] += wgt * bf2f(u.y >> 16);
                acc[4] += wgt * bf2f(u.z & 0xffffu);
                acc[5] += wgt * bf2f(u.z >> 16);
                acc[6] += wgt * bf2f(u.w & 0xffffu);
                acc[7] += wgt * bf2f(u.w >> 16);
            }
        }
    }
    const size_t bq = (size_t)b * NQ + q;
    uint4 out;
    out.x = (uint32_t)f2bf(acc[0]) | ((uint32_t)f2bf(acc[1]) << 16);
    out.y = (uint32_t)f2bf(acc[2]) | ((uint32_t)f2bf(acc[3]) << 16);
    out.z = (uint32_t)f2bf(acc[4]) | ((uint32_t)f2bf(acc[5]) << 16);
    out.w = (uint32_t)f2bf(acc[6]) | ((uint32_t)f2bf(acc[7]) << 16);
    *(uint4*)((char*)oatt + (bq * 256 + h * 32 + dg * 8) * 2) = out;
}

// ---------------------------------------------------------------------------
extern "C" void kernel_launch(void* const* d_in, const int* in_sizes, int n_in,
                              void* d_out, int out_size, void* d_ws, size_t ws_size,
                              hipStream_t stream) {
    const float* query  = (const float*)d_in[0];
    const float* refp   = (const float*)d_in[1];
    const float* value  = (const float*)d_in[2];
    const float* w_off  = (const float*)d_in[3];
    const float* b_off  = (const float*)d_in[4];
    const float* w_attn = (const float*)d_in[5];
    const float* b_attn = (const float*)d_in[6];
    const float* w_val  = (const float*)d_in[7];
    const float* b_val  = (const float*)d_in[8];
    const float* w_out  = (const float*)d_in[9];
    const float* b_out  = (const float*)d_in[10];

    char* ws = (char*)d_ws;
    uint16_t* v     = (uint16_t*)(ws);                    //  67108864 B  [b][h][pix][32]
    uint16_t* oatt  = (uint16_t*)(ws + 67108864);         //  33554432 B  [bq][256]
    float*    locs  = (float*)(ws + 100663296);           //  16777216 B  head-major
    float*    attnw = (float*)(ws + 117440512);           //   8388608 B  head-major
    uint16_t* wTval = (uint16_t*)(ws + 125829120);        //    131072 B
    uint16_t* wTout = (uint16_t*)(ws + 125960192);        //    131072 B
    uint16_t* wTcat = (uint16_t*)(ws + 126091264);        //     49152 B

    pack_w<<<256, 256, 0, stream>>>(w_val, w_out, w_off, w_attn, wTval, wTout, wTcat);
    // value projection: [131072 x 256] f32 @ wTval -> v (plane-major bf16)
    gemm_k256<true, false, true><<<dim3(1024, 2), 256, 0, stream>>>(value, wTval, v, b_val, 131072);
    // query projections + softmax + locations (head-major records)
    proj_kernel<<<1024, 256, 0, stream>>>(query, wTcat, b_off, b_attn, refp, locs, attnw);
    // bilinear sampling -> out_attn bf16
    sample_kernel<<<8192, 256, 0, stream>>>(v, locs, attnw, oatt);
    // output projection: [65536 x 256] bf16 @ wTout + b_out -> f32 d_out
    gemm_k256<false, true, false><<<dim3(512, 2), 256, 0, stream>>>(oatt, wTout, (float*)d_out, b_out, 65536);
}

// Round 3
// 175.359 us; speedup vs baseline: 1.3712x; 1.0514x over previous
//
#include <hip/hip_runtime.h>
#include <stdint.h>

#define NQ 8192
#define BSZ 8
#define NH 8
#define NP 4
#define HD 32
#define EMBED 256
#define IMG 128          // H == W == 128
#define NPIX (IMG*IMG)

typedef __attribute__((ext_vector_type(8))) short short8v;   // 8 bf16 (4 VGPR)
typedef __attribute__((ext_vector_type(4))) float f32x4;

static __device__ __forceinline__ float bf2f(uint32_t u) {
    union { uint32_t i; float f; } x; x.i = u << 16; return x.f;
}
static __device__ __forceinline__ uint16_t f2bf(float f) {
    union { float f; uint32_t i; } x; x.f = f;
    uint32_t r = x.i + 0x7fffu + ((x.i >> 16) & 1u);   // RNE
    return (uint16_t)(r >> 16);
}
static __device__ __forceinline__ void gload_lds16(const void* g, void* l) {
    __builtin_amdgcn_global_load_lds(
        (const __attribute__((address_space(1))) unsigned int*)g,
        (__attribute__((address_space(3))) unsigned int*)l, 16, 0, 0);
}

// ---------------------------------------------------------------------------
// pack: build transposed bf16 weights.  wT[n][k] = w[k][n]
// ---------------------------------------------------------------------------
__global__ void pack_w(const float* __restrict__ w_val, const float* __restrict__ w_out,
                       const float* __restrict__ w_off, const float* __restrict__ w_attn,
                       uint16_t* __restrict__ wTval, uint16_t* __restrict__ wTout,
                       uint16_t* __restrict__ wTcat) {
    int k = blockIdx.x;          // 0..255
    int n = threadIdx.x;         // 0..255
    wTval[n * 256 + k] = f2bf(w_val[k * 256 + n]);
    wTout[n * 256 + k] = f2bf(w_out[k * 256 + n]);
    if (n < 64)       wTcat[n * 256 + k]        = f2bf(w_off[k * 64 + n]);
    else if (n < 96)  wTcat[n * 256 + k]        = f2bf(w_attn[k * 32 + (n - 64)]);
}

// ---------------------------------------------------------------------------
// GEMM  C[M x 256] = A[M x 256] * B[256 x 256] (+bias), K=256
//  BK=32, LDS 32KB total -> 4 blocks/CU.  Row stride 64B,
//  swizzle byte ^= ((row>>1)&3)<<4  (2-way residual conflict = free).
//  PLANE: C is v[b][h][pix][32] bf16, written via LDS-transposed epilogue
//         with fully coalesced dwordx4 stores.
// ---------------------------------------------------------------------------
static __device__ __forceinline__ int swz32(int row) { return ((row >> 1) & 3) << 4; }

template<bool A_F32, bool OUT_F32, bool PLANE>
__global__ __launch_bounds__(256, 4)
void gemm_k256(const void* __restrict__ Ap, const uint16_t* __restrict__ BT,
               void* __restrict__ Cp, const float* __restrict__ bias, int M) {
    __shared__ uint16_t SMEM[16384];               // 32 KB
    uint16_t* As[2] = { SMEM,        SMEM + 4096 };
    uint16_t* Bs[2] = { SMEM + 8192, SMEM + 12288 };
    const int tid = threadIdx.x;
    const int w = tid >> 6, l = tid & 63;
    const int bm = blockIdx.x, bn = blockIdx.y;

    f32x4 acc[4][4] = {};

    auto stageB = [&](int buf, int kt) {
#pragma unroll
        for (int c = 0; c < 2; ++c) {
            int chunk = w * 2 + c;
            int loff = chunk * 1024 + l * 16;
            int row = loff >> 6, colb = loff & 63;
            const char* src = (const char*)BT + (size_t)(bn * 128 + row) * 512
                              + kt * 64 + (colb ^ swz32(row));
            gload_lds16(src, (char*)Bs[buf] + chunk * 1024);
        }
    };
    auto stageA = [&](int buf, int kt) {
        if constexpr (!A_F32) {
#pragma unroll
            for (int c = 0; c < 2; ++c) {
                int chunk = w * 2 + c;
                int loff = chunk * 1024 + l * 16;
                int row = loff >> 6, colb = loff & 63;
                const char* src = (const char*)Ap + (size_t)(bm * 128 + row) * 512
                                  + kt * 64 + (colb ^ swz32(row));
                gload_lds16(src, (char*)As[buf] + chunk * 1024);
            }
        } else {
            // f32 A: batch all loads, then cvt+ds_write.
            float4 f[2][2];
#pragma unroll
            for (int c = 0; c < 2; ++c) {
                int row = c * 64 + (tid >> 2);
                const float* src = (const float*)Ap + (size_t)(bm * 128 + row) * 256
                                   + kt * 32 + (tid & 3) * 8;
                f[c][0] = ((const float4*)src)[0];
                f[c][1] = ((const float4*)src)[1];
            }
#pragma unroll
            for (int c = 0; c < 2; ++c) {
                int row = c * 64 + (tid >> 2);
                int colb = (tid & 3) * 16;
                uint4 pk;
                pk.x = (uint32_t)f2bf(f[c][0].x) | ((uint32_t)f2bf(f[c][0].y) << 16);
                pk.y = (uint32_t)f2bf(f[c][0].z) | ((uint32_t)f2bf(f[c][0].w) << 16);
                pk.z = (uint32_t)f2bf(f[c][1].x) | ((uint32_t)f2bf(f[c][1].y) << 16);
                pk.w = (uint32_t)f2bf(f[c][1].z) | ((uint32_t)f2bf(f[c][1].w) << 16);
                *(uint4*)((char*)As[buf] + row * 64 + (colb ^ swz32(row))) = pk;
            }
        }
    };

    const int wr = (w >> 1) * 64, wc = (w & 1) * 64;
    int buf = 0;
    stageB(0, 0); stageA(0, 0);
    __syncthreads();
#pragma unroll
    for (int kt = 0; kt < 8; ++kt) {
        if (kt < 7) { stageB(buf ^ 1, kt + 1); stageA(buf ^ 1, kt + 1); }
        short8v a[4], b[4];
        const int kb = (l >> 4) * 16;   // 8 bf16 k-slice within BK=32
#pragma unroll
        for (int m = 0; m < 4; ++m) {
            int row = wr + m * 16 + (l & 15);
            a[m] = *(const short8v*)((const char*)As[buf] + row * 64 + (kb ^ swz32(row)));
        }
#pragma unroll
        for (int n = 0; n < 4; ++n) {
            int col = wc + n * 16 + (l & 15);
            b[n] = *(const short8v*)((const char*)Bs[buf] + col * 64 + (kb ^ swz32(col)));
        }
#pragma unroll
        for (int m = 0; m < 4; ++m)
#pragma unroll
            for (int n = 0; n < 4; ++n)
                acc[m][n] = __builtin_amdgcn_mfma_f32_16x16x32_bf16(a[m], b[n], acc[m][n], 0, 0, 0);
        __syncthreads();
        buf ^= 1;
    }

    const int r0l = wr + ((l >> 4) * 4);
    const int c0l = wc + (l & 15);
    if constexpr (PLANE) {
        // acc -> swizzled LDS C-tile [128][128] u16, then coalesced plane stores
        uint16_t* Cs = SMEM;
#pragma unroll
        for (int m = 0; m < 4; ++m)
#pragma unroll
            for (int n = 0; n < 4; ++n) {
                int lcol = c0l + n * 16;
                float bv = bias[bn * 128 + lcol];
#pragma unroll
                for (int r = 0; r < 4; ++r) {
                    int lrow = r0l + m * 16 + r;
                    *(uint16_t*)((char*)Cs + ((lrow * 256 + lcol * 2) ^ ((lrow & 7) << 4)))
                        = f2bf(acc[m][n][r] + bv);
                }
            }
        __syncthreads();
#pragma unroll
        for (int i = 0; i < 8; ++i) {
            int f16i = i * 2048 + tid * 8;
            int lrow = f16i >> 7, lcol = f16i & 127;
            uint4 d = *(const uint4*)((const char*)Cs + ((lrow * 256 + lcol * 2) ^ ((lrow & 7) << 4)));
            int gr = bm * 128 + lrow;
            int b_ = gr >> 14, pix = gr & 16383;
            int h_ = bn * 4 + (lcol >> 5), d_ = lcol & 31;
            *(uint4*)((char*)Cp + (((size_t)(b_ * 8 + h_)) << 20) + (size_t)pix * 64 + d_ * 2) = d;
        }
    } else {
        const int r0 = bm * 128 + r0l;
        const int c0 = bn * 128 + c0l;
#pragma unroll
        for (int m = 0; m < 4; ++m)
#pragma unroll
            for (int n = 0; n < 4; ++n) {
                int col = c0 + n * 16;
                float bv = bias[col];
#pragma unroll
                for (int r = 0; r < 4; ++r) {
                    int row = r0 + m * 16 + r;
                    float val = acc[m][n][r] + bv;
                    if constexpr (OUT_F32)
                        ((float*)Cp)[(size_t)row * 256 + col] = val;
                    else
                        ((uint16_t*)Cp)[(size_t)row * 256 + col] = f2bf(val);
                }
            }
    }
}

// ---------------------------------------------------------------------------
// proj: per 64 query rows, GEMM query[64x256] @ wTcat^T -> scores[64x96],
// then per (row, head): softmax + sampling locations, written HEAD-MAJOR:
//   itemH = ((b*8+h)*8192 + q);  locs[itemH][8], attnw[itemH][4]
// ---------------------------------------------------------------------------
__global__ __launch_bounds__(256, 2)
void proj_kernel(const float* __restrict__ Q, const uint16_t* __restrict__ WTcat,
                 const float* __restrict__ b_off, const float* __restrict__ b_attn,
                 const float* __restrict__ refp,
                 float* __restrict__ locs, float* __restrict__ attnw) {
    __shared__ uint16_t Bs[96 * 256];   // 48KB, [col][k], swizzled (512B rows)
    __shared__ uint16_t As[64 * 256];   // 32KB, [row][k], swizzled; reused as scores
    const int tid = threadIdx.x, w = tid >> 6, l = tid & 63;
    const int blk = blockIdx.x;

#pragma unroll
    for (int c = 0; c < 12; ++c) {
        int loff = (w * 12 + c) * 1024;
        int lofl = loff + l * 16;
        int row = lofl >> 9, colb = lofl & 511;
        const char* src = (const char*)WTcat + (size_t)row * 512 + (colb ^ ((row & 7) << 4));
        gload_lds16(src, (char*)Bs + loff);
    }
#pragma unroll
    for (int c = 0; c < 8; ++c) {
        int loff = tid * 16 + c * 4096;
        int row = loff >> 9, colb = loff & 511;
        const float* src = Q + (size_t)(blk * 64 + row) * 256 + (colb >> 1);
        float4 f0 = *(const float4*)src;
        float4 f1 = *(const float4*)(src + 4);
        uint4 pk;
        pk.x = (uint32_t)f2bf(f0.x) | ((uint32_t)f2bf(f0.y) << 16);
        pk.y = (uint32_t)f2bf(f0.z) | ((uint32_t)f2bf(f0.w) << 16);
        pk.z = (uint32_t)f2bf(f1.x) | ((uint32_t)f2bf(f1.y) << 16);
        pk.w = (uint32_t)f2bf(f1.z) | ((uint32_t)f2bf(f1.w) << 16);
        *(uint4*)((char*)As + row * 512 + (colb ^ ((row & 7) << 4))) = pk;
    }
    __syncthreads();

    f32x4 acc[6] = {};
    const int arow = w * 16 + (l & 15);
#pragma unroll
    for (int ks = 0; ks < 8; ++ks) {
        const int kb = ks * 64 + (l >> 4) * 16;
        short8v a = *(const short8v*)((const char*)As + arow * 512 + (kb ^ ((arow & 7) << 4)));
#pragma unroll
        for (int n = 0; n < 6; ++n) {
            int col = n * 16 + (l & 15);
            short8v b = *(const short8v*)((const char*)Bs + col * 512 + (kb ^ ((col & 7) << 4)));
            acc[n] = __builtin_amdgcn_mfma_f32_16x16x32_bf16(a, b, acc[n], 0, 0, 0);
        }
    }
    __syncthreads();
    float* scores = (float*)As;   // [64][96]
#pragma unroll
    for (int n = 0; n < 6; ++n)
#pragma unroll
        for (int r = 0; r < 4; ++r)
            scores[(w * 16 + (l >> 4) * 4 + r) * 96 + n * 16 + (l & 15)] = acc[n][r];
    __syncthreads();

    for (int it = tid; it < 512; it += 256) {
        int row = it >> 3, h = it & 7;
        int gq = blk * 64 + row;                       // b*NQ + q
        int b = gq >> 13, q = gq & 8191;
        size_t itemH = ((size_t)(b * 8 + h) << 13) | q;
        float s0 = scores[row * 96 + 64 + h * 4 + 0] + b_attn[h * 4 + 0];
        float s1 = scores[row * 96 + 64 + h * 4 + 1] + b_attn[h * 4 + 1];
        float s2 = scores[row * 96 + 64 + h * 4 + 2] + b_attn[h * 4 + 2];
        float s3 = scores[row * 96 + 64 + h * 4 + 3] + b_attn[h * 4 + 3];
        float mx = fmaxf(fmaxf(s0, s1), fmaxf(s2, s3));
        float e0 = __expf(s0 - mx), e1 = __expf(s1 - mx);
        float e2 = __expf(s2 - mx), e3 = __expf(s3 - mx);
        float inv = 1.0f / (e0 + e1 + e2 + e3);
        float rx = refp[gq * 2 + 0] * 128.0f - 0.5f;
        float ry = refp[gq * 2 + 1] * 128.0f - 0.5f;
        float ew[4] = { e0, e1, e2, e3 };
#pragma unroll
        for (int p = 0; p < 4; ++p) {
            float ox = scores[row * 96 + h * 8 + p * 2 + 0] + b_off[h * 8 + p * 2 + 0];
            float oy = scores[row * 96 + h * 8 + p * 2 + 1] + b_off[h * 8 + p * 2 + 1];
            locs[itemH * 8 + p * 2 + 0] = rx + ox;
            locs[itemH * 8 + p * 2 + 1] = ry + oy;
            attnw[itemH * 4 + p] = ew[p] * inv;
        }
    }
}

// ---------------------------------------------------------------------------
// sample: plane-major v[b][h][16384][32] bf16 (1MB per (b,h) plane).
// XCD-pinned: blockIdx&7 = h; 4 lanes/item, dwordx4 gathers.
// ---------------------------------------------------------------------------
__global__ __launch_bounds__(256)
void sample_kernel(const uint16_t* __restrict__ v, const float* __restrict__ locs,
                   const float* __restrict__ attnw, uint16_t* __restrict__ oatt) {
    const int bid = blockIdx.x;          // 8192 blocks
    const int h = bid & 7;
    const int rest = bid >> 3;           // 0..1023
    const int b = rest >> 7;             // 0..7
    const int chunk = rest & 127;        // 0..127
    const int qloc = threadIdx.x >> 2;   // 0..63
    const int dg = threadIdx.x & 3;      // dims dg*8..dg*8+7
    const int q = chunk * 64 + qloc;
    const size_t itemH = ((size_t)(b * 8 + h) << 13) | q;
    const char* plane = (const char*)v + ((size_t)(b * 8 + h) << 20);   // 1MB planes

    float4 l01 = ((const float4*)locs)[itemH * 2 + 0];
    float4 l23 = ((const float4*)locs)[itemH * 2 + 1];
    float4 aw4 = ((const float4*)attnw)[itemH];
    float pxs[4] = { l01.x, l01.z, l23.x, l23.z };
    float pys[4] = { l01.y, l01.w, l23.y, l23.w };
    float aws[4] = { aw4.x, aw4.y, aw4.z, aw4.w };

    float acc[8] = {};
#pragma unroll
    for (int p = 0; p < 4; ++p) {
        float px = pxs[p], py = pys[p], aw = aws[p];
        float fx = floorf(px), fy = floorf(py);
        float wx = px - fx, wy = py - fy;
        int x0 = (int)fx, y0 = (int)fy;
#pragma unroll
        for (int cy = 0; cy < 2; ++cy) {
            int yy = y0 + cy;
            float wyv = cy ? wy : 1.f - wy;
            bool yok = (unsigned)yy < (unsigned)IMG;
            int yc = min(max(yy, 0), IMG - 1);
#pragma unroll
            for (int cx = 0; cx < 2; ++cx) {
                int xx = x0 + cx;
                bool ok = yok && ((unsigned)xx < (unsigned)IMG);
                int xc = min(max(xx, 0), IMG - 1);
                float wgt = ok ? aw * (cx ? wx : 1.f - wx) * wyv : 0.f;
                const uint4 u = *(const uint4*)(plane + ((size_t)(yc * IMG + xc) << 6) + dg * 16);
                acc[0] += wgt * bf2f(u.x & 0xffffu);
                acc[1] += wgt * bf2f(u.x >> 16);
                acc[2] += wgt * bf2f(u.y & 0xffffu);
                acc[3] += wgt * bf2f(u.y >> 16);
                acc[4] += wgt * bf2f(u.z & 0xffffu);
                acc[5] += wgt * bf2f(u.z >> 16);
                acc[6] += wgt * bf2f(u.w & 0xffffu);
                acc[7] += wgt * bf2f(u.w >> 16);
            }
        }
    }
    const size_t bq = (size_t)b * NQ + q;
    uint4 out;
    out.x = (uint32_t)f2bf(acc[0]) | ((uint32_t)f2bf(acc[1]) << 16);
    out.y = (uint32_t)f2bf(acc[2]) | ((uint32_t)f2bf(acc[3]) << 16);
    out.z = (uint32_t)f2bf(acc[4]) | ((uint32_t)f2bf(acc[5]) << 16);
    out.w = (uint32_t)f2bf(acc[6]) | ((uint32_t)f2bf(acc[7]) << 16);
    *(uint4*)((char*)oatt + (bq * 256 + h * 32 + dg * 8) * 2) = out;
}

// ---------------------------------------------------------------------------
extern "C" void kernel_launch(void* const* d_in, const int* in_sizes, int n_in,
                              void* d_out, int out_size, void* d_ws, size_t ws_size,
                              hipStream_t stream) {
    const float* query  = (const float*)d_in[0];
    const float* refp   = (const float*)d_in[1];
    const float* value  = (const float*)d_in[2];
    const float* w_off  = (const float*)d_in[3];
    const float* b_off  = (const float*)d_in[4];
    const float* w_attn = (const float*)d_in[5];
    const float* b_attn = (const float*)d_in[6];
    const float* w_val  = (const float*)d_in[7];
    const float* b_val  = (const float*)d_in[8];
    const float* w_out  = (const float*)d_in[9];
    const float* b_out  = (const float*)d_in[10];

    char* ws = (char*)d_ws;
    uint16_t* v     = (uint16_t*)(ws);                    //  67108864 B  [b][h][pix][32]
    uint16_t* oatt  = (uint16_t*)(ws + 67108864);         //  33554432 B  [bq][256]
    float*    locs  = (float*)(ws + 100663296);           //  16777216 B  head-major
    float*    attnw = (float*)(ws + 117440512);           //   8388608 B  head-major
    uint16_t* wTval = (uint16_t*)(ws + 125829120);        //    131072 B
    uint16_t* wTout = (uint16_t*)(ws + 125960192);        //    131072 B
    uint16_t* wTcat = (uint16_t*)(ws + 126091264);        //     49152 B

    pack_w<<<256, 256, 0, stream>>>(w_val, w_out, w_off, w_attn, wTval, wTout, wTcat);
    // value projection: [131072 x 256] f32 @ wTval -> v (plane-major bf16)
    gemm_k256<true, false, true><<<dim3(1024, 2), 256, 0, stream>>>(value, wTval, v, b_val, 131072);
    // query projections + softmax + locations (head-major records)
    proj_kernel<<<1024, 256, 0, stream>>>(query, wTcat, b_off, b_attn, refp, locs, attnw);
    // bilinear sampling -> out_attn bf16
    sample_kernel<<<8192, 256, 0, stream>>>(v, locs, attnw, oatt);
    // output projection: [65536 x 256] bf16 @ wTout + b_out -> f32 d_out
    gemm_k256<false, true, false><<<dim3(512, 2), 256, 0, stream>>>(oatt, wTout, (float*)d_out, b_out, 65536);
}